// Round 14
// baseline (568.639 us; speedup 1.0000x reference)
//
#include <hip/hip_runtime.h>

#define N_NODES  50000
#define N_EDGES  600000
#define N_GRAPHS 512
#define DIM      128
#define N_FEAT   78
#define N_LAYERS 4
#define BN_EPS   1e-5f
#define SLOT_CAP 64
#define LDA      136

#define TW_BLOCKS   640                       // 10*16384/256 weight-transpose blocks
#define EDGE_BLOCKS ((N_EDGES + 255) / 256)   // 2344
#define ZERO_BLOCKS 512
#define BG_BLOCKS (TW_BLOCKS + EDGE_BLOCKS + 1 + ZERO_BLOCKS)

typedef __attribute__((ext_vector_type(8))) _Float16 f16x8;
typedef __attribute__((ext_vector_type(4))) float f32x4;

static __device__ __forceinline__ short f2h(float f) {
    _Float16 h = (_Float16)f;
    union { _Float16 h; short s; } u; u.h = h;
    return u.s;
}
static __device__ __forceinline__ float h2f(ushort s) {
    union { ushort s; _Float16 h; } u; u.s = s;
    return (float)u.h;
}

// ------- fused prep: weight transpose + adjacency build + gcount + aff + zeroing -------

__global__ __launch_bounds__(256) void build_graph(const float* __restrict__ ini_w1,
                                                   const float* __restrict__ ini_w2,
                                                   const float* __restrict__ gw1,
                                                   const float* __restrict__ gw2,
                                                   short* __restrict__ wt,
                                                   const int* __restrict__ src,
                                                   const int* __restrict__ dst,
                                                   const int* __restrict__ batch,
                                                   int* __restrict__ cnt,
                                                   ushort* __restrict__ slot,
                                                   int* __restrict__ gcnt,
                                                   float* __restrict__ aff,
                                                   float* __restrict__ gsum,
                                                   float* __restrict__ gssq) {
    int b = blockIdx.x;
    int tid = threadIdx.x;
    if (b < TW_BLOCKS) {
        int gid = b * 256 + tid;
        int m = gid >> 14;
        int idx = gid & 16383;
        int n = idx >> 7;
        int k = idx & 127;
        const float* s;
        int K = 128;
        if (m == 0) { s = ini_w1; K = N_FEAT; }
        else if (m == 1) s = ini_w2;
        else if (m < 6) s = gw1 + (m - 2) * 16384;
        else s = gw2 + (m - 6) * 16384;
        float v = (k < K) ? s[k * 128 + n] : 0.f;
        wt[m * 16384 + n * 128 + k] = f2h(v);
    } else if (b < TW_BLOCKS + EDGE_BLOCKS) {
        int e = (b - TW_BLOCKS) * 256 + tid;
        if (e < N_EDGES) {
            int d = dst[e];
            int p = atomicAdd(&cnt[d], 1);
            if (p < SLOT_CAP) slot[d * SLOT_CAP + p] = (ushort)src[e];
        }
        if (e < N_NODES) atomicAdd(&gcnt[batch[e]], 1);
    } else if (b == TW_BLOCKS + EDGE_BLOCKS) {
        if (tid < 128) {
            aff[tid] = 1.0f;
            aff[128 + tid] = 0.0f;
        }
    } else {
        int zb = b - TW_BLOCKS - EDGE_BLOCKS - 1;
        float4 z = make_float4(0.f, 0.f, 0.f, 0.f);
        float* base = (zb < 256) ? gsum : gssq;
        int off = (zb & 255) * 1024 + tid * 4;
        *(float4*)&base[off] = z;
    }
}

// ---------------- ini MLP: z0 = relu(x@W1+b1)@W2+b2, W direct from global (L2) -------

__global__ __launch_bounds__(256) void gemm_ini(const float* __restrict__ A,
                                                const short* __restrict__ Wt1,
                                                const float* __restrict__ b1,
                                                const short* __restrict__ Wt2,
                                                const float* __restrict__ b2,
                                                ushort* __restrict__ C) {
    __shared__ short As[64 * LDA];
    int tid = threadIdx.x;
    int row0 = blockIdx.x * 64;

    #pragma unroll
    for (int j = 0; j < 32; ++j) {
        int lin = tid + j * 256;
        int r = lin >> 7;
        int k = lin & 127;
        int gr = row0 + r;
        float v = 0.f;
        if (gr < N_NODES && k < N_FEAT) v = A[gr * N_FEAT + k];
        As[r * LDA + k] = f2h(v);
    }
    __syncthreads();

    int wave = tid >> 6;
    int lane = tid & 63;
    int rw = wave >> 1;
    int cw = wave & 1;
    int lm = lane & 15;
    int quad = lane >> 4;

    f32x4 acc[2][4];
    #pragma unroll
    for (int mt = 0; mt < 2; ++mt)
        #pragma unroll
        for (int nt = 0; nt < 4; ++nt)
            acc[mt][nt] = (f32x4){0.f, 0.f, 0.f, 0.f};

    #pragma unroll
    for (int ks = 0; ks < 4; ++ks) {
        int kb = ks * 32 + quad * 8;
        f16x8 a0 = *(const f16x8*)&As[(rw * 32 + lm) * LDA + kb];
        f16x8 a1 = *(const f16x8*)&As[(rw * 32 + 16 + lm) * LDA + kb];
        #pragma unroll
        for (int nt = 0; nt < 4; ++nt) {
            int col = cw * 64 + nt * 16 + lm;
            f16x8 b = *(const f16x8*)&Wt1[col * 128 + kb];
            acc[0][nt] = __builtin_amdgcn_mfma_f32_16x16x32_f16(a0, b, acc[0][nt], 0, 0, 0);
            acc[1][nt] = __builtin_amdgcn_mfma_f32_16x16x32_f16(a1, b, acc[1][nt], 0, 0, 0);
        }
    }
    __syncthreads();

    ushort* Cs = (ushort*)As;
    #pragma unroll
    for (int nt = 0; nt < 4; ++nt) {
        int col = cw * 64 + nt * 16 + lm;
        float bv = b1[col];
        #pragma unroll
        for (int mt = 0; mt < 2; ++mt) {
            #pragma unroll
            for (int r = 0; r < 4; ++r) {
                int row = rw * 32 + mt * 16 + quad * 4 + r;
                Cs[row * LDA + col] = (ushort)f2h(fmaxf(acc[mt][nt][r] + bv, 0.f));
            }
        }
    }
    __syncthreads();

    #pragma unroll
    for (int mt = 0; mt < 2; ++mt)
        #pragma unroll
        for (int nt = 0; nt < 4; ++nt)
            acc[mt][nt] = (f32x4){0.f, 0.f, 0.f, 0.f};
    #pragma unroll
    for (int ks = 0; ks < 4; ++ks) {
        int kb = ks * 32 + quad * 8;
        f16x8 a0 = *(const f16x8*)&As[(rw * 32 + lm) * LDA + kb];
        f16x8 a1 = *(const f16x8*)&As[(rw * 32 + 16 + lm) * LDA + kb];
        #pragma unroll
        for (int nt = 0; nt < 4; ++nt) {
            int col = cw * 64 + nt * 16 + lm;
            f16x8 b = *(const f16x8*)&Wt2[col * 128 + kb];
            acc[0][nt] = __builtin_amdgcn_mfma_f32_16x16x32_f16(a0, b, acc[0][nt], 0, 0, 0);
            acc[1][nt] = __builtin_amdgcn_mfma_f32_16x16x32_f16(a1, b, acc[1][nt], 0, 0, 0);
        }
    }
    __syncthreads();

    #pragma unroll
    for (int nt = 0; nt < 4; ++nt) {
        int col = cw * 64 + nt * 16 + lm;
        float bv = b2[col];
        #pragma unroll
        for (int mt = 0; mt < 2; ++mt) {
            #pragma unroll
            for (int r = 0; r < 4; ++r) {
                int row = rw * 32 + mt * 16 + quad * 4 + r;
                Cs[row * LDA + col] = (ushort)f2h(acc[mt][nt][r] + bv);
            }
        }
    }
    __syncthreads();
    #pragma unroll
    for (int j = 0; j < 4; ++j) {
        int lin = tid + j * 256;
        int r = lin >> 4;
        int kc = lin & 15;
        int gr = row0 + r;
        if (gr < N_NODES)
            *(uint4*)&C[gr * 128 + kc * 8] = *(const uint4*)&Cs[r * LDA + kc * 8];
    }
}

// ------- fused GIN layer: gather-aggregate (BN-folded) into LDS + MLP + stats --------
// LDS = 17.7 KB (A-tile only; W from global/L2) -> ~5-6 blocks/CU so the
// latency-bound gather overlaps other blocks' MFMA.

template <int STORE>
__global__ __launch_bounds__(256) void layer_fused(const ushort* __restrict__ Z,
                                                   const int* __restrict__ cnt,
                                                   const ushort* __restrict__ slot,
                                                   const float* __restrict__ aff,
                                                   const short* __restrict__ Wt1,
                                                   const float* __restrict__ b1,
                                                   const short* __restrict__ Wt2,
                                                   const float* __restrict__ b2,
                                                   ushort* __restrict__ Znext,
                                                   const int* __restrict__ batch,
                                                   float* __restrict__ gsum,
                                                   float* __restrict__ gssq) {
    __shared__ short As[64 * LDA];
    __shared__ int sb[64];
    int tid = threadIdx.x;
    int row0 = blockIdx.x * 64;

    if (tid < 64) {
        int n = row0 + tid;
        sb[tid] = (n < N_NODES) ? batch[n] : -1;
    }

    // gather-aggregate directly into As (4 passes of 16 nodes, 16 lanes/node)
    union U { uint4 u; _Float16 h[8]; };
    union I { uint4 u; ushort s[8]; };
    const uint4* z4 = (const uint4*)Z;
    int lane = tid & 15;
    float sA[8], tA[8];
    #pragma unroll
    for (int j = 0; j < 8; ++j) {
        sA[j] = aff[lane * 8 + j];
        tA[j] = aff[128 + lane * 8 + j];
    }
    #pragma unroll
    for (int pass = 0; pass < 4; ++pass) {
        int rloc = pass * 16 + (tid >> 4);
        int node = row0 + rloc;
        if (node < N_NODES) {
            U zu; zu.u = z4[node * 16 + lane];
            float v[8];
            #pragma unroll
            for (int j = 0; j < 8; ++j) v[j] = (float)zu.h[j];
            int dtrue = cnt[node];
            int d = min(dtrue, SLOT_CAP);
            const ushort* sl = slot + node * SLOT_CAP;
            int e = 0;
            for (; e + 8 <= d; e += 8) {
                I si; si.u = *(const uint4*)&sl[e];
                U u[8];
                #pragma unroll
                for (int q = 0; q < 8; ++q) u[q].u = z4[(int)si.s[q] * 16 + lane];
                #pragma unroll
                for (int j = 0; j < 8; ++j) {
                    float a = ((float)u[0].h[j] + (float)u[1].h[j]) +
                              ((float)u[2].h[j] + (float)u[3].h[j]);
                    float bq = ((float)u[4].h[j] + (float)u[5].h[j]) +
                               ((float)u[6].h[j] + (float)u[7].h[j]);
                    v[j] += a + bq;
                }
            }
            if (e + 4 <= d) {
                int s0 = sl[e], s1 = sl[e + 1], s2 = sl[e + 2], s3 = sl[e + 3];
                U u0, u1, u2, u3;
                u0.u = z4[s0 * 16 + lane];
                u1.u = z4[s1 * 16 + lane];
                u2.u = z4[s2 * 16 + lane];
                u3.u = z4[s3 * 16 + lane];
                #pragma unroll
                for (int j = 0; j < 8; ++j)
                    v[j] += ((float)u0.h[j] + (float)u1.h[j]) +
                            ((float)u2.h[j] + (float)u3.h[j]);
                e += 4;
            }
            for (; e < d; ++e) {
                U u; u.u = z4[(int)sl[e] * 16 + lane];
                #pragma unroll
                for (int j = 0; j < 8; ++j) v[j] += (float)u.h[j];
            }
            float dsc = 1.0f + (float)dtrue;
            U ou;
            #pragma unroll
            for (int j = 0; j < 8; ++j)
                ou.h[j] = (_Float16)(sA[j] * v[j] + dsc * tA[j]);
            *(uint4*)&As[rloc * LDA + lane * 8] = ou.u;
        } else {
            uint4 zz = {0u, 0u, 0u, 0u};
            *(uint4*)&As[rloc * LDA + lane * 8] = zz;
        }
    }
    __syncthreads();

    int wave = tid >> 6;
    int lane64 = tid & 63;
    int rw = wave >> 1;
    int cw = wave & 1;
    int lm = lane64 & 15;
    int quad = lane64 >> 4;

    f32x4 acc[2][4];
    #pragma unroll
    for (int mt = 0; mt < 2; ++mt)
        #pragma unroll
        for (int nt = 0; nt < 4; ++nt)
            acc[mt][nt] = (f32x4){0.f, 0.f, 0.f, 0.f};

    // phase 1: T = A @ W1 (B from global, L2-resident)
    #pragma unroll
    for (int ks = 0; ks < 4; ++ks) {
        int kb = ks * 32 + quad * 8;
        f16x8 a0 = *(const f16x8*)&As[(rw * 32 + lm) * LDA + kb];
        f16x8 a1 = *(const f16x8*)&As[(rw * 32 + 16 + lm) * LDA + kb];
        #pragma unroll
        for (int nt = 0; nt < 4; ++nt) {
            int col = cw * 64 + nt * 16 + lm;
            f16x8 b = *(const f16x8*)&Wt1[col * 128 + kb];
            acc[0][nt] = __builtin_amdgcn_mfma_f32_16x16x32_f16(a0, b, acc[0][nt], 0, 0, 0);
            acc[1][nt] = __builtin_amdgcn_mfma_f32_16x16x32_f16(a1, b, acc[1][nt], 0, 0, 0);
        }
    }
    __syncthreads();

    ushort* Cs = (ushort*)As;
    #pragma unroll
    for (int nt = 0; nt < 4; ++nt) {
        int col = cw * 64 + nt * 16 + lm;
        float bv = b1[col];
        #pragma unroll
        for (int mt = 0; mt < 2; ++mt) {
            #pragma unroll
            for (int r = 0; r < 4; ++r) {
                int row = rw * 32 + mt * 16 + quad * 4 + r;
                Cs[row * LDA + col] = (ushort)f2h(fmaxf(acc[mt][nt][r] + bv, 0.f));
            }
        }
    }
    __syncthreads();

    // phase 2: Z = T @ W2
    #pragma unroll
    for (int mt = 0; mt < 2; ++mt)
        #pragma unroll
        for (int nt = 0; nt < 4; ++nt)
            acc[mt][nt] = (f32x4){0.f, 0.f, 0.f, 0.f};
    #pragma unroll
    for (int ks = 0; ks < 4; ++ks) {
        int kb = ks * 32 + quad * 8;
        f16x8 a0 = *(const f16x8*)&As[(rw * 32 + lm) * LDA + kb];
        f16x8 a1 = *(const f16x8*)&As[(rw * 32 + 16 + lm) * LDA + kb];
        #pragma unroll
        for (int nt = 0; nt < 4; ++nt) {
            int col = cw * 64 + nt * 16 + lm;
            f16x8 b = *(const f16x8*)&Wt2[col * 128 + kb];
            acc[0][nt] = __builtin_amdgcn_mfma_f32_16x16x32_f16(a0, b, acc[0][nt], 0, 0, 0);
            acc[1][nt] = __builtin_amdgcn_mfma_f32_16x16x32_f16(a1, b, acc[1][nt], 0, 0, 0);
        }
    }
    __syncthreads();

    #pragma unroll
    for (int nt = 0; nt < 4; ++nt) {
        int col = cw * 64 + nt * 16 + lm;
        float bv = b2[col];
        #pragma unroll
        for (int mt = 0; mt < 2; ++mt) {
            #pragma unroll
            for (int r = 0; r < 4; ++r) {
                int row = rw * 32 + mt * 16 + quad * 4 + r;
                Cs[row * LDA + col] = (ushort)f2h(fmaxf(acc[mt][nt][r] + bv, 0.f));
            }
        }
    }
    __syncthreads();
    if (STORE) {
        #pragma unroll
        for (int j = 0; j < 4; ++j) {
            int lin = tid + j * 256;
            int r = lin >> 4;
            int kc = lin & 15;
            int gr = row0 + r;
            if (gr < N_NODES)
                *(uint4*)&Znext[gr * 128 + kc * 8] = *(const uint4*)&Cs[r * LDA + kc * 8];
        }
    }
    // per-graph column sums/sumsqs
    {
        int c = tid & 127;
        int rbase = (tid >> 7) * 32;
        int curg = sb[rbase];
        float rs = 0.f, rss = 0.f;
        for (int r = rbase; r < rbase + 32; ++r) {
            int g = sb[r];
            if (g < 0) break;
            if (g != curg) {
                atomicAdd(&gsum[curg * 128 + c], rs);
                atomicAdd(&gssq[curg * 128 + c], rss);
                rs = 0.f; rss = 0.f; curg = g;
            }
            float v = h2f(Cs[r * LDA + c]);
            rs += v; rss += v * v;
        }
        if (curg >= 0) {
            atomicAdd(&gsum[curg * 128 + c], rs);
            atomicAdd(&gssq[curg * 128 + c], rss);
        }
    }
}

// ---------------- finalize: Σ_g gsum/gssq -> BN affine (s, t) ----------------

__global__ __launch_bounds__(512) void finalize_bn(const float* __restrict__ gsum,
                                                   const float* __restrict__ gssq,
                                                   const float* __restrict__ gamma,
                                                   const float* __restrict__ beta,
                                                   float* __restrict__ aff) {
    __shared__ float rs[512], rss[512];
    int t = threadIdx.x;
    int d = t & 127, grp = t >> 7;
    float s = 0.f, ss = 0.f;
    for (int g = grp; g < N_GRAPHS; g += 4) {
        s += gsum[g * 128 + d];
        ss += gssq[g * 128 + d];
    }
    rs[t] = s; rss[t] = ss;
    __syncthreads();
    if (t < 128) {
        s = rs[t] + rs[t + 128] + rs[t + 256] + rs[t + 384];
        ss = rss[t] + rss[t + 128] + rss[t + 256] + rss[t + 384];
        const float invN = 1.0f / (float)N_NODES;
        float m = s * invN;
        float var = ss * invN - m * m;
        float sc = gamma[d] * rsqrtf(var + BN_EPS);
        aff[d] = sc;
        aff[128 + d] = beta[d] - m * sc;
    }
}

// ---------------- combine ----------------

__global__ __launch_bounds__(256) void combine(const float* __restrict__ gsum,
                                               const float* __restrict__ aff,
                                               const int* __restrict__ gcnt,
                                               const float* __restrict__ LW,
                                               const float* __restrict__ LB,
                                               float* __restrict__ out) {
    int gid = blockIdx.x * 256 + threadIdx.x;
    if (gid >= N_GRAPHS * 128) return;
    int g = gid >> 7;
    int d = gid & 127;
    float c = (float)gcnt[g];
    float o = c * LB[0];
    #pragma unroll
    for (int l = 0; l < N_LAYERS; ++l) {
        float s = aff[(l + 1) * 256 + d];
        float t = aff[(l + 1) * 256 + 128 + d];
        o += LW[l] * (s * gsum[(l * N_GRAPHS + g) * 128 + d] + c * t);
    }
    out[gid] = o;
}

// ---------------- host launcher ----------------

extern "C" void kernel_launch(void* const* d_in, const int* in_sizes, int n_in,
                              void* d_out, int out_size, void* d_ws, size_t ws_size,
                              hipStream_t stream) {
    const float* x      = (const float*)d_in[0];
    const int*   ei     = (const int*)d_in[1];
    const int*   batch  = (const int*)d_in[2];
    const float* ini_w1 = (const float*)d_in[3];
    const float* ini_b1 = (const float*)d_in[4];
    const float* ini_w2 = (const float*)d_in[5];
    const float* ini_b2 = (const float*)d_in[6];
    const float* gw1    = (const float*)d_in[7];
    const float* gb1    = (const float*)d_in[8];
    const float* gw2    = (const float*)d_in[9];
    const float* gb2    = (const float*)d_in[10];
    const float* gamma  = (const float*)d_in[11];
    const float* beta   = (const float*)d_in[12];
    const float* lw     = (const float*)d_in[13];
    const float* lb     = (const float*)d_in[14];
    float* out = (float*)d_out;

    char* p = (char*)d_ws;
    auto carve = [&](size_t bytes) -> char* {
        char* q = p;
        p += (bytes + 255) & ~(size_t)255;
        return q;
    };
    ushort* z0   = (ushort*)carve(sizeof(ushort) * N_NODES * DIM);
    ushort* z1   = (ushort*)carve(sizeof(ushort) * N_NODES * DIM);
    float* aff   = (float*)carve(sizeof(float) * (N_LAYERS + 1) * 256);
    float* gsum  = (float*)carve(sizeof(float) * N_LAYERS * N_GRAPHS * DIM);
    float* gssq  = (float*)carve(sizeof(float) * N_LAYERS * N_GRAPHS * DIM);
    short* wbf   = (short*)carve(sizeof(short) * 10 * 128 * 128);
    int* gcnt    = (int*)carve(sizeof(int) * N_GRAPHS);
    int* cnt     = (int*)carve(sizeof(int) * N_NODES);
    ushort* slot = (ushort*)carve(sizeof(ushort) * N_NODES * SLOT_CAP);

    const int* src = ei;
    const int* dst = ei + N_EDGES;

    hipMemsetAsync(cnt, 0, sizeof(int) * N_NODES, stream);
    hipMemsetAsync(gcnt, 0, sizeof(int) * N_GRAPHS, stream);

    build_graph<<<BG_BLOCKS, 256, 0, stream>>>(ini_w1, ini_w2, gw1, gw2, wbf,
                                               src, dst, batch, cnt, slot, gcnt,
                                               aff, gsum, gssq);

    int gblocks = (N_NODES + 63) / 64;
    gemm_ini<<<gblocks, 256, 0, stream>>>(x, wbf, ini_b1, wbf + 16384, ini_b2, z0);

    ushort* zprev = z0;
    ushort* znext = z1;
    for (int i = 0; i < N_LAYERS; ++i) {
        if (i < N_LAYERS - 1) {
            layer_fused<1><<<gblocks, 256, 0, stream>>>(
                zprev, cnt, slot, aff + i * 256,
                wbf + (2 + i) * 16384, gb1 + i * DIM,
                wbf + (6 + i) * 16384, gb2 + i * DIM, znext, batch,
                gsum + i * N_GRAPHS * DIM, gssq + i * N_GRAPHS * DIM);
        } else {
            layer_fused<0><<<gblocks, 256, 0, stream>>>(
                zprev, cnt, slot, aff + i * 256,
                wbf + (2 + i) * 16384, gb1 + i * DIM,
                wbf + (6 + i) * 16384, gb2 + i * DIM, znext, batch,
                gsum + i * N_GRAPHS * DIM, gssq + i * N_GRAPHS * DIM);
        }
        finalize_bn<<<1, 512, 0, stream>>>(gsum + i * N_GRAPHS * DIM,
                                           gssq + i * N_GRAPHS * DIM,
                                           gamma + i * DIM, beta + i * DIM,
                                           aff + (i + 1) * 256);
        ushort* tmp = zprev; zprev = znext; znext = tmp;
    }
    combine<<<(N_GRAPHS * 128 + 255) / 256, 256, 0, stream>>>(
        gsum, aff, gcnt, lw, lb, out);
}

// Round 15
// 517.567 us; speedup vs baseline: 1.0987x; 1.0987x over previous
//
#include <hip/hip_runtime.h>

#define N_NODES  50000
#define N_EDGES  600000
#define N_GRAPHS 512
#define DIM      128
#define N_FEAT   78
#define N_LAYERS 4
#define BN_EPS   1e-5f
#define SLOT_CAP 64
#define LDA      136

#define EDGE_BLOCKS ((N_EDGES + 255) / 256)   // 2344
#define ZERO_BLOCKS 512                       // zero 2 MB of gsum+gssq (1 MB each)
#define BG_BLOCKS (EDGE_BLOCKS + 1 + ZERO_BLOCKS)

typedef __attribute__((ext_vector_type(8))) _Float16 f16x8;
typedef __attribute__((ext_vector_type(4))) float f32x4;

static __device__ __forceinline__ short f2h(float f) {
    _Float16 h = (_Float16)f;
    union { _Float16 h; short s; } u; u.h = h;
    return u.s;
}
static __device__ __forceinline__ float h2f(ushort s) {
    union { ushort s; _Float16 h; } u; u.s = s;
    return (float)u.h;
}

// ---------------- graph build: ushort slotted adjacency + gcount + affine + zeroing ----

__global__ __launch_bounds__(256) void build_graph(const int* __restrict__ src,
                                                   const int* __restrict__ dst,
                                                   const int* __restrict__ batch,
                                                   int* __restrict__ cnt,
                                                   ushort* __restrict__ slot,
                                                   int* __restrict__ gcnt,
                                                   float* __restrict__ aff,
                                                   float* __restrict__ gsum,
                                                   float* __restrict__ gssq) {
    int b = blockIdx.x;
    int tid = threadIdx.x;
    if (b < EDGE_BLOCKS) {
        int e = b * 256 + tid;
        if (e < N_EDGES) {
            int d = dst[e];
            int p = atomicAdd(&cnt[d], 1);
            if (p < SLOT_CAP) slot[d * SLOT_CAP + p] = (ushort)src[e];
        }
        if (e < N_NODES) atomicAdd(&gcnt[batch[e]], 1);
    } else if (b == EDGE_BLOCKS) {
        if (tid < 128) {
            aff[tid] = 1.0f;
            aff[128 + tid] = 0.0f;
        }
    } else {
        int zb = b - EDGE_BLOCKS - 1;      // 0..511
        float4 z = make_float4(0.f, 0.f, 0.f, 0.f);
        float* base = (zb < 256) ? gsum : gssq;
        int off = (zb & 255) * 1024 + tid * 4;   // 1024 floats per block
        *(float4*)&base[off] = z;
    }
}

// ---------------- aggregation with folded BN affine ----------------
// A[n] = s ⊙ (Z[n] + Σ_{j->n} Z[j]) + (1+deg[n]) ⊙ t      (fp16 in/out, fp32 math)

__global__ __launch_bounds__(256) void aggregate_h(const ushort* __restrict__ Z,
                                                   const int* __restrict__ cnt,
                                                   const ushort* __restrict__ slot,
                                                   const float* __restrict__ aff,
                                                   ushort* __restrict__ A) {
    int node = blockIdx.x * 16 + (threadIdx.x >> 4);
    if (node >= N_NODES) return;
    int lane = threadIdx.x & 15;
    union U { uint4 u; _Float16 h[8]; };
    union I { uint4 u; ushort s[8]; };
    const uint4* z4 = (const uint4*)Z;
    U zu; zu.u = z4[node * 16 + lane];
    float v[8];
    #pragma unroll
    for (int j = 0; j < 8; ++j) v[j] = (float)zu.h[j];
    int dtrue = cnt[node];
    int d = min(dtrue, SLOT_CAP);
    const ushort* sl = slot + node * SLOT_CAP;
    int e = 0;
    for (; e + 8 <= d; e += 8) {
        I si; si.u = *(const uint4*)&sl[e];
        U u[8];
        #pragma unroll
        for (int q = 0; q < 8; ++q) u[q].u = z4[(int)si.s[q] * 16 + lane];
        #pragma unroll
        for (int j = 0; j < 8; ++j) {
            float a = ((float)u[0].h[j] + (float)u[1].h[j]) +
                      ((float)u[2].h[j] + (float)u[3].h[j]);
            float b = ((float)u[4].h[j] + (float)u[5].h[j]) +
                      ((float)u[6].h[j] + (float)u[7].h[j]);
            v[j] += a + b;
        }
    }
    if (e + 4 <= d) {
        int s0 = sl[e], s1 = sl[e + 1], s2 = sl[e + 2], s3 = sl[e + 3];
        U u0, u1, u2, u3;
        u0.u = z4[s0 * 16 + lane];
        u1.u = z4[s1 * 16 + lane];
        u2.u = z4[s2 * 16 + lane];
        u3.u = z4[s3 * 16 + lane];
        #pragma unroll
        for (int j = 0; j < 8; ++j)
            v[j] += ((float)u0.h[j] + (float)u1.h[j]) +
                    ((float)u2.h[j] + (float)u3.h[j]);
        e += 4;
    }
    for (; e < d; ++e) {
        U u; u.u = z4[(int)sl[e] * 16 + lane];
        #pragma unroll
        for (int j = 0; j < 8; ++j) v[j] += (float)u.h[j];
    }
    float dsc = 1.0f + (float)dtrue;
    U ou;
    #pragma unroll
    for (int j = 0; j < 8; ++j) {
        float s = aff[lane * 8 + j];
        float t = aff[128 + lane * 8 + j];
        ou.h[j] = (_Float16)(s * v[j] + dsc * t);
    }
    ((uint4*)A)[node * 16 + lane] = ou.u;
}

// ---------------- weight pre-transpose: W[K][128] fp32 -> Wt[n][k] fp16 ----------------

__global__ __launch_bounds__(256) void transpose_weights(const float* __restrict__ ini_w1,
                                                         const float* __restrict__ ini_w2,
                                                         const float* __restrict__ gw1,
                                                         const float* __restrict__ gw2,
                                                         short* __restrict__ wt) {
    int gid = blockIdx.x * 256 + threadIdx.x;
    if (gid >= 10 * 16384) return;
    int m = gid >> 14;
    int idx = gid & 16383;
    int n = idx >> 7;
    int k = idx & 127;
    const float* src;
    int K = 128;
    if (m == 0) { src = ini_w1; K = N_FEAT; }
    else if (m == 1) src = ini_w2;
    else if (m < 6) src = gw1 + (m - 2) * 16384;
    else src = gw2 + (m - 6) * 16384;
    float v = (k < K) ? src[k * 128 + n] : 0.f;
    wt[m * 16384 + n * 128 + k] = f2h(v);
}

// ---------------- fused 2-layer MLP: C = act2(relu(A@W1+b1)@W2+b2) ----------------

template <int K_IN, int FP32A, int RELU2, int STATS>
__global__ __launch_bounds__(256) void gemm_mlp(const void* __restrict__ Ain,
                                                const short* __restrict__ Wt1,
                                                const float* __restrict__ b1,
                                                const short* __restrict__ Wt2,
                                                const float* __restrict__ b2,
                                                ushort* __restrict__ C,
                                                const int* __restrict__ batch,
                                                float* __restrict__ gsum,
                                                float* __restrict__ gssq) {
    __shared__ short As[64 * LDA];
    __shared__ short Ws[128 * LDA];
    __shared__ int sb[64];
    int tid = threadIdx.x;
    int row0 = blockIdx.x * 64;

    #pragma unroll
    for (int j = 0; j < 8; ++j) {
        int lin = tid + j * 256;
        int n = lin >> 4;
        int kc = lin & 15;
        *(uint4*)&Ws[n * LDA + kc * 8] = *(const uint4*)&Wt1[n * 128 + kc * 8];
    }
    if (FP32A) {
        const float* A = (const float*)Ain;
        #pragma unroll
        for (int j = 0; j < 32; ++j) {
            int lin = tid + j * 256;
            int r = lin >> 7;
            int k = lin & 127;
            int gr = row0 + r;
            float v = 0.f;
            if (gr < N_NODES && k < K_IN) v = A[gr * K_IN + k];
            As[r * LDA + k] = f2h(v);
        }
    } else {
        const ushort* A = (const ushort*)Ain;
        #pragma unroll
        for (int j = 0; j < 4; ++j) {
            int lin = tid + j * 256;
            int r = lin >> 4;
            int kc = lin & 15;
            int gr = row0 + r;
            uint4 v = {0u, 0u, 0u, 0u};
            if (gr < N_NODES) v = *(const uint4*)&A[gr * 128 + kc * 8];
            *(uint4*)&As[r * LDA + kc * 8] = v;
        }
    }
    if (STATS && tid < 64) {
        int n = row0 + tid;
        sb[tid] = (n < N_NODES) ? batch[n] : -1;
    }
    __syncthreads();

    int wave = tid >> 6;
    int lane = tid & 63;
    int rw = wave >> 1;
    int cw = wave & 1;
    int lm = lane & 15;
    int quad = lane >> 4;

    f32x4 acc[2][4];
    #pragma unroll
    for (int mt = 0; mt < 2; ++mt)
        #pragma unroll
        for (int nt = 0; nt < 4; ++nt)
            acc[mt][nt] = (f32x4){0.f, 0.f, 0.f, 0.f};

    #pragma unroll
    for (int ks = 0; ks < 4; ++ks) {
        int kb = ks * 32 + quad * 8;
        f16x8 a0 = *(const f16x8*)&As[(rw * 32 + lm) * LDA + kb];
        f16x8 a1 = *(const f16x8*)&As[(rw * 32 + 16 + lm) * LDA + kb];
        #pragma unroll
        for (int nt = 0; nt < 4; ++nt) {
            f16x8 b = *(const f16x8*)&Ws[(cw * 64 + nt * 16 + lm) * LDA + kb];
            acc[0][nt] = __builtin_amdgcn_mfma_f32_16x16x32_f16(a0, b, acc[0][nt], 0, 0, 0);
            acc[1][nt] = __builtin_amdgcn_mfma_f32_16x16x32_f16(a1, b, acc[1][nt], 0, 0, 0);
        }
    }
    __syncthreads();

    ushort* Cs = (ushort*)As;
    #pragma unroll
    for (int nt = 0; nt < 4; ++nt) {
        int col = cw * 64 + nt * 16 + lm;
        float bv = b1[col];
        #pragma unroll
        for (int mt = 0; mt < 2; ++mt) {
            #pragma unroll
            for (int r = 0; r < 4; ++r) {
                int row = rw * 32 + mt * 16 + quad * 4 + r;
                Cs[row * LDA + col] = (ushort)f2h(fmaxf(acc[mt][nt][r] + bv, 0.f));
            }
        }
    }
    #pragma unroll
    for (int j = 0; j < 8; ++j) {
        int lin = tid + j * 256;
        int n = lin >> 4;
        int kc = lin & 15;
        *(uint4*)&Ws[n * LDA + kc * 8] = *(const uint4*)&Wt2[n * 128 + kc * 8];
    }
    __syncthreads();

    #pragma unroll
    for (int mt = 0; mt < 2; ++mt)
        #pragma unroll
        for (int nt = 0; nt < 4; ++nt)
            acc[mt][nt] = (f32x4){0.f, 0.f, 0.f, 0.f};
    #pragma unroll
    for (int ks = 0; ks < 4; ++ks) {
        int kb = ks * 32 + quad * 8;
        f16x8 a0 = *(const f16x8*)&As[(rw * 32 + lm) * LDA + kb];
        f16x8 a1 = *(const f16x8*)&As[(rw * 32 + 16 + lm) * LDA + kb];
        #pragma unroll
        for (int nt = 0; nt < 4; ++nt) {
            f16x8 b = *(const f16x8*)&Ws[(cw * 64 + nt * 16 + lm) * LDA + kb];
            acc[0][nt] = __builtin_amdgcn_mfma_f32_16x16x32_f16(a0, b, acc[0][nt], 0, 0, 0);
            acc[1][nt] = __builtin_amdgcn_mfma_f32_16x16x32_f16(a1, b, acc[1][nt], 0, 0, 0);
        }
    }
    __syncthreads();

    #pragma unroll
    for (int nt = 0; nt < 4; ++nt) {
        int col = cw * 64 + nt * 16 + lm;
        float bv = b2[col];
        #pragma unroll
        for (int mt = 0; mt < 2; ++mt) {
            #pragma unroll
            for (int r = 0; r < 4; ++r) {
                int row = rw * 32 + mt * 16 + quad * 4 + r;
                float o = acc[mt][nt][r] + bv;
                if (RELU2) o = fmaxf(o, 0.f);
                Cs[row * LDA + col] = (ushort)f2h(o);
            }
        }
    }
    __syncthreads();
    #pragma unroll
    for (int j = 0; j < 4; ++j) {
        int lin = tid + j * 256;
        int r = lin >> 4;
        int kc = lin & 15;
        int gr = row0 + r;
        if (gr < N_NODES)
            *(uint4*)&C[gr * 128 + kc * 8] = *(const uint4*)&Cs[r * LDA + kc * 8];
    }
    if (STATS) {
        int c = tid & 127;
        int rbase = (tid >> 7) * 32;
        int curg = sb[rbase];
        float rs = 0.f, rss = 0.f;
        for (int r = rbase; r < rbase + 32; ++r) {
            int g = sb[r];
            if (g < 0) break;
            if (g != curg) {
                atomicAdd(&gsum[curg * 128 + c], rs);
                atomicAdd(&gssq[curg * 128 + c], rss);
                rs = 0.f; rss = 0.f; curg = g;
            }
            float v = h2f(Cs[r * LDA + c]);
            rs += v; rss += v * v;
        }
        if (curg >= 0) {
            atomicAdd(&gsum[curg * 128 + c], rs);
            atomicAdd(&gssq[curg * 128 + c], rss);
        }
    }
}

// ---------------- finalize: Σ_g gsum/gssq -> BN affine (s, t) ----------------

__global__ __launch_bounds__(512) void finalize_bn(const float* __restrict__ gsum,
                                                   const float* __restrict__ gssq,
                                                   const float* __restrict__ gamma,
                                                   const float* __restrict__ beta,
                                                   float* __restrict__ aff) {
    __shared__ float rs[512], rss[512];
    int t = threadIdx.x;
    int d = t & 127, grp = t >> 7;
    float s = 0.f, ss = 0.f;
    for (int g = grp; g < N_GRAPHS; g += 4) {
        s += gsum[g * 128 + d];
        ss += gssq[g * 128 + d];
    }
    rs[t] = s; rss[t] = ss;
    __syncthreads();
    if (t < 128) {
        s = rs[t] + rs[t + 128] + rs[t + 256] + rs[t + 384];
        ss = rss[t] + rss[t + 128] + rss[t + 256] + rss[t + 384];
        const float invN = 1.0f / (float)N_NODES;
        float m = s * invN;
        float var = ss * invN - m * m;
        float sc = gamma[d] * rsqrtf(var + BN_EPS);
        aff[d] = sc;
        aff[128 + d] = beta[d] - m * sc;
    }
}

// ---------------- combine ----------------

__global__ __launch_bounds__(256) void combine(const float* __restrict__ gsum,
                                               const float* __restrict__ aff,
                                               const int* __restrict__ gcnt,
                                               const float* __restrict__ LW,
                                               const float* __restrict__ LB,
                                               float* __restrict__ out) {
    int gid = blockIdx.x * 256 + threadIdx.x;
    if (gid >= N_GRAPHS * 128) return;
    int g = gid >> 7;
    int d = gid & 127;
    float c = (float)gcnt[g];
    float o = c * LB[0];
    #pragma unroll
    for (int l = 0; l < N_LAYERS; ++l) {
        float s = aff[(l + 1) * 256 + d];
        float t = aff[(l + 1) * 256 + 128 + d];
        o += LW[l] * (s * gsum[(l * N_GRAPHS + g) * 128 + d] + c * t);
    }
    out[gid] = o;
}

// ---------------- host launcher ----------------

extern "C" void kernel_launch(void* const* d_in, const int* in_sizes, int n_in,
                              void* d_out, int out_size, void* d_ws, size_t ws_size,
                              hipStream_t stream) {
    const float* x      = (const float*)d_in[0];
    const int*   ei     = (const int*)d_in[1];
    const int*   batch  = (const int*)d_in[2];
    const float* ini_w1 = (const float*)d_in[3];
    const float* ini_b1 = (const float*)d_in[4];
    const float* ini_w2 = (const float*)d_in[5];
    const float* ini_b2 = (const float*)d_in[6];
    const float* gw1    = (const float*)d_in[7];
    const float* gb1    = (const float*)d_in[8];
    const float* gw2    = (const float*)d_in[9];
    const float* gb2    = (const float*)d_in[10];
    const float* gamma  = (const float*)d_in[11];
    const float* beta   = (const float*)d_in[12];
    const float* lw     = (const float*)d_in[13];
    const float* lb     = (const float*)d_in[14];
    float* out = (float*)d_out;

    char* p = (char*)d_ws;
    auto carve = [&](size_t bytes) -> char* {
        char* q = p;
        p += (bytes + 255) & ~(size_t)255;
        return q;
    };
    ushort* z0   = (ushort*)carve(sizeof(ushort) * N_NODES * DIM);
    ushort* z1   = (ushort*)carve(sizeof(ushort) * N_NODES * DIM);
    ushort* abuf = (ushort*)carve(sizeof(ushort) * N_NODES * DIM);
    float* aff   = (float*)carve(sizeof(float) * (N_LAYERS + 1) * 256);
    float* gsum  = (float*)carve(sizeof(float) * N_LAYERS * N_GRAPHS * DIM);
    float* gssq  = (float*)carve(sizeof(float) * N_LAYERS * N_GRAPHS * DIM);
    short* wbf   = (short*)carve(sizeof(short) * 10 * 128 * 128);
    int* gcnt    = (int*)carve(sizeof(int) * N_GRAPHS);
    int* cnt     = (int*)carve(sizeof(int) * N_NODES);
    ushort* slot = (ushort*)carve(sizeof(ushort) * N_NODES * SLOT_CAP);

    const int* src = ei;
    const int* dst = ei + N_EDGES;

    hipMemsetAsync(cnt, 0, sizeof(int) * N_NODES, stream);
    hipMemsetAsync(gcnt, 0, sizeof(int) * N_GRAPHS, stream);

    transpose_weights<<<(10 * 16384 + 255) / 256, 256, 0, stream>>>(
        ini_w1, ini_w2, gw1, gw2, wbf);

    build_graph<<<BG_BLOCKS, 256, 0, stream>>>(src, dst, batch, cnt, slot, gcnt,
                                               aff, gsum, gssq);

    int gblocks = (N_NODES + 63) / 64;
    gemm_mlp<N_FEAT, 1, 0, 0><<<gblocks, 256, 0, stream>>>(
        x, wbf, ini_b1, wbf + 16384, ini_b2, z0, nullptr, nullptr, nullptr);

    ushort* zprev = z0;
    ushort* znext = z1;
    for (int i = 0; i < N_LAYERS; ++i) {
        aggregate_h<<<(N_NODES + 15) / 16, 256, 0, stream>>>(
            zprev, cnt, slot, aff + i * 256, abuf);
        gemm_mlp<128, 0, 1, 1><<<gblocks, 256, 0, stream>>>(
            abuf, wbf + (2 + i) * 16384, gb1 + i * DIM,
            wbf + (6 + i) * 16384, gb2 + i * DIM, znext, batch,
            gsum + i * N_GRAPHS * DIM, gssq + i * N_GRAPHS * DIM);
        finalize_bn<<<1, 512, 0, stream>>>(gsum + i * N_GRAPHS * DIM,
                                           gssq + i * N_GRAPHS * DIM,
                                           gamma + i * DIM, beta + i * DIM,
                                           aff + (i + 1) * 256);
        ushort* tmp = zprev; zprev = znext; znext = tmp;
    }
    combine<<<(N_GRAPHS * 128 + 255) / 256, 256, 0, stream>>>(
        gsum, aff, gcnt, lw, lb, out);
}